// Round 13
// baseline (260.806 us; speedup 1.0000x reference)
//
#include <hip/hip_runtime.h>
#include <stdint.h>

#define IN_F  4096
#define OUT_F 4096
#define BW    512
#define WB2   1280   // padded k-window per 256-col tile: [bcol-512, bcol+768)
#define BM    256
#define BN    256

typedef __bf16 bf16x8 __attribute__((ext_vector_type(8)));
typedef float  f32x4  __attribute__((ext_vector_type(4)));

__device__ __forceinline__ int band_start(int o) {
    if (o <= 512)  return o * 513 + ((o * (o - 1)) >> 1);
    if (o <= 3584) return 393472 + (o - 512) * 1025;
    const int d = o - 3584;
    return 3542272 + (((1024 + 4609 - o) * d) >> 1);
}

__device__ __forceinline__ uint16_t f32_to_bf16(float f) {
    uint32_t u = __builtin_bit_cast(uint32_t, f);
    u += 0x7FFFu + ((u >> 16) & 1u);   // RNE
    return (uint16_t)(u >> 16);
}

// ---- pass 1 (single dispatch): x fp32->bf16 dense  ∥  band densify -> wd
//      blocks [0,2048): x ; blocks [2048,2128): w  (independent, run concurrently)
__global__ __launch_bounds__(256) void cvt_xw(const float* __restrict__ x,
                                              const float* __restrict__ wv,
                                              uint16_t* __restrict__ xb,
                                              uint16_t* __restrict__ wd, int n4) {
    const int b = blockIdx.x;
    if (b < 2048) {
        for (int i = b * 256 + threadIdx.x; i < n4; i += 2048 * 256) {
            const float4 v = reinterpret_cast<const float4*>(x)[i];
            const uint32_t lo = (uint32_t)f32_to_bf16(v.x) | ((uint32_t)f32_to_bf16(v.y) << 16);
            const uint32_t hi = (uint32_t)f32_to_bf16(v.z) | ((uint32_t)f32_to_bf16(v.w) << 16);
            reinterpret_cast<uint2*>(xb)[i] = make_uint2(lo, hi);
        }
    } else {
        const int nw = OUT_F * WB2;
        for (int e = (b - 2048) * 256 + threadIdx.x; e < nw; e += 80 * 256) {
            const int o = e / WB2;                    // const-div -> mul_hi
            const int j = e - o * WB2;
            const int i = (o & ~(BM - 1)) - BW + j;
            uint16_t v = 0;
            if (i >= o - BW && i <= o + BW && i >= 0 && i < IN_F) {
                const int lo = (o > BW) ? (o - BW) : 0;
                v = f32_to_bf16(wv[band_start(o) + (i - lo)]);
            }
            wd[e] = v;
        }
    }
}

// ---- pass 2: R10 GEMM verbatim (best measured: 95.6 us, MfmaUtil 33%, conflicts 0)
// ring-9 half-tile units (144 KB), counted vmcnt(2), ONE barrier per K64 tile,
// no setprio, persistent 2 row-jobs (1 block/CU), bx-grouped XCD mapping.
__global__ __launch_bounds__(512, 1) void band_gemm_v10(
    const uint16_t* __restrict__ xb,
    const uint16_t* __restrict__ wd,
    const float* __restrict__ bias,
    float* __restrict__ out)
{
    __shared__ __align__(128) uint8_t lds[9 * 16384];   // 144 KB, 9 unit slots

    const int id  = blockIdx.x;
    const int bx  = 2 * (id & 7) + ((id >> 3) & 1);
    const int byg = id >> 4;                 // rows byg and byg+16
    const int bcol = bx * BN;
    const int brow0 = byg * BM;

    const int wlo    = bcol - BW;
    const int kstart = wlo > 0 ? wlo : 0;
    const int kend   = (bcol + BN + BW) < IN_F ? (bcol + BN + BW) : IN_F;
    const int nt     = (kend - kstart) >> 6;      // 12/16/20 K64 tiles
    const int j0     = kstart - wlo;

    const int tid  = threadIdx.x;
    const int w    = tid >> 6;
    const int lane = tid & 63;
    const int ln   = lane & 15;
    const int kc   = lane >> 4;
    const int wm   = w >> 2;            // 0..1  (M half, 128 rows)
    const int wn   = w & 3;             // 0..3  (N quarter, 64 cols)

    const int srow = tid >> 3;          // 0..63
    const int csrc = (tid & 7) ^ (srow & 7);
    const uint16_t* aSrc0 = xb + (size_t)(brow0 + srow) * IN_F + kstart + csrc * 8;
    const uint16_t* aSrc1 = aSrc0 + (size_t)16 * BM * IN_F;      // rows +4096
    const uint16_t* bSrc  = wd + (size_t)(bcol + srow) * WB2 + j0 + csrc * 8;

#define GLOAD(srcp, dst_off)                                                             \
    __builtin_amdgcn_global_load_lds(                                                    \
        (const __attribute__((address_space(1))) uint32_t*)(srcp),                       \
        (__attribute__((address_space(3))) uint32_t*)(lds + (dst_off) + (w << 10)),      \
        16, 0, 0)

#define STG_UNIT(AS, w_, j_, slot_) {                                                    \
        if (((j_) & 1) == 0) {                                                           \
            const uint16_t* p_ = (AS) + (size_t)(((j_) >> 1) * 128) * IN_F + (w_) * 64;  \
            GLOAD(p_, (slot_) << 14);                                                    \
            GLOAD(p_ + (size_t)64 * IN_F, ((slot_) << 14) + 8192);                       \
        } else {                                                                         \
            const uint16_t* p_ = bSrc + (size_t)(((j_) >> 1) * 128) * WB2 + (w_) * 64;   \
            GLOAD(p_, (slot_) << 14);                                                    \
            GLOAD(p_ + (size_t)64 * WB2, ((slot_) << 14) + 8192);                        \
        } }

    const int cswz = (kc ^ (ln & 7)) << 4;

#define LD_A(BASE, MQ) {                                                                 \
    _Pragma("unroll")                                                                    \
    for (int s_ = 0; s_ < 4; ++s_) {                                                     \
        const int off_ = (BASE) + (((MQ) * 64 + s_ * 16 + ln) << 7) + cswz;              \
        am[s_][0] = *(const bf16x8*)(lds + off_);                                        \
        am[s_][1] = *(const bf16x8*)(lds + (off_ ^ 64));                                 \
    } }
#define LD_B(DST, BASE, NQ) {                                                            \
    _Pragma("unroll")                                                                    \
    for (int s_ = 0; s_ < 2; ++s_) {                                                     \
        const int off_ = (BASE) + (((wn & 1) * 64 + (NQ) * 32 + s_ * 16 + ln) << 7) + cswz; \
        DST[s_][0] = *(const bf16x8*)(lds + off_);                                       \
        DST[s_][1] = *(const bf16x8*)(lds + (off_ ^ 64));                                \
    } }
#define MFMAPH(MROW, NCOL, BB) {                                                         \
    _Pragma("unroll")                                                                    \
    for (int a_ = 0; a_ < 4; ++a_) {                                                     \
        _Pragma("unroll")                                                                \
        for (int n_ = 0; n_ < 2; ++n_) {                                                 \
            acc[(MROW) + a_][(NCOL) + n_] = __builtin_amdgcn_mfma_f32_16x16x32_bf16(     \
                am[a_][0], BB[n_][0], acc[(MROW) + a_][(NCOL) + n_], 0, 0, 0);           \
            acc[(MROW) + a_][(NCOL) + n_] = __builtin_amdgcn_mfma_f32_16x16x32_bf16(     \
                am[a_][1], BB[n_][1], acc[(MROW) + a_][(NCOL) + n_], 0, 0, 0);           \
        } } }

#define PRO(AS) {                                                                        \
    STG_UNIT(AS, 0, 0, 0); STG_UNIT(AS, 0, 1, 1); STG_UNIT(AS, 0, 2, 2);                 \
    STG_UNIT(AS, 0, 3, 3); STG_UNIT(AS, 1, 0, 4); }

#define KLOOP(AS) {                                                                      \
    int s4v = 0;                                                                         \
    for (int v = 0; v < nt; ++v) {                                                       \
        int sA = s4v + (wm << 1);            if (sA >= 9) sA -= 9;                       \
        int sB = s4v + 1 + ((wn >> 1) << 1); if (sB >= 9) sB -= 9;                       \
        const int aBase = sA << 14, bBase = sB << 14;                                    \
        int st0 = s4v + 5; if (st0 >= 9) st0 -= 9;                                       \
        int st1 = st0 + 1; if (st1 >= 9) st1 -= 9;                                       \
        int st2 = st1 + 1; if (st2 >= 9) st2 -= 9;                                       \
        int st3 = st2 + 1; if (st3 >= 9) st3 -= 9;                                       \
        const bool stg_q012 = (v + 1 < nt);                                              \
        const bool stg_q3   = (v + 2 < nt);                                              \
        LD_A(aBase, 0);                                                                  \
        LD_B(bn0, bBase, 0);                                                             \
        if (stg_q012) STG_UNIT(AS, v + 1, 1, st0);                                       \
        MFMAPH(0, 0, bn0);                                                               \
        LD_B(bn1, bBase, 1);                                                             \
        if (stg_q012) STG_UNIT(AS, v + 1, 2, st1);                                       \
        MFMAPH(0, 2, bn1);                                                               \
        LD_A(aBase, 1);                                                                  \
        if (stg_q012) STG_UNIT(AS, v + 1, 3, st2);                                       \
        MFMAPH(4, 2, bn1);                                                               \
        if (stg_q3) STG_UNIT(AS, v + 2, 0, st3);                                         \
        MFMAPH(4, 0, bn0);                                                               \
        if (v + 1 < nt) {                                                                \
            if (v + 2 < nt) { asm volatile("s_waitcnt vmcnt(2)" ::: "memory"); }         \
            else            { asm volatile("s_waitcnt vmcnt(0)" ::: "memory"); }         \
            __builtin_amdgcn_s_barrier();                                                \
        }                                                                                \
        s4v += 4; if (s4v >= 9) s4v -= 9;                                                \
    } }

#define EPI(BROWX) {                                                                     \
    _Pragma("unroll")                                                                    \
    for (int a_ = 0; a_ < 8; ++a_) {                                                     \
        _Pragma("unroll")                                                                \
        for (int q_ = 0; q_ < 4; ++q_) {                                                 \
            const int row_ = (BROWX) + wm * 128 + a_ * 16 + (kc << 2) + q_;              \
            float* po_ = out + (size_t)row_ * OUT_F + ocol;                              \
            _Pragma("unroll")                                                            \
            for (int n_ = 0; n_ < 4; ++n_)                                               \
                po_[n_ * 16] = acc[a_][n_][q_] + bsv[n_];                                 \
        } } }

    const int ocol = bcol + wn * 64 + ln;
    float bsv[4];
    #pragma unroll
    for (int n = 0; n < 4; ++n) bsv[n] = bias[ocol + n * 16];

    f32x4 acc[8][4] = {};
    bf16x8 am[4][2], bn0[2][2], bn1[2][2];

    // ---- row-tile g=0
    PRO(aSrc0);
    asm volatile("s_waitcnt vmcnt(2)" ::: "memory");
    __builtin_amdgcn_s_barrier();
    KLOOP(aSrc0);
    __builtin_amdgcn_s_barrier();            // slot safety: all g0 reads complete

    // ---- g=1 prologue; epilogue-0 stores drain under g1 compute
    PRO(aSrc1);
    asm volatile("s_waitcnt vmcnt(2)" ::: "memory");
    __builtin_amdgcn_s_barrier();
    EPI(brow0);
    #pragma unroll
    for (int a = 0; a < 8; ++a)
        #pragma unroll
        for (int n = 0; n < 4; ++n) acc[a][n] = (f32x4){0.f, 0.f, 0.f, 0.f};
    KLOOP(aSrc1);
    EPI(brow0 + 16 * BM);

#undef STG_UNIT
#undef GLOAD
#undef PRO
#undef KLOOP
#undef EPI
}

// ---- fallback (ws too small / odd M): fp32 tiled kernel, known correct
__global__ __launch_bounds__(256) void band_gemm_f32(
    const float* __restrict__ x, const float* __restrict__ wv,
    const float* __restrict__ bias, float* __restrict__ out, int M)
{
    __shared__ float Xs[128][33];
    __shared__ float Ws[32][130];
    const int tid = threadIdx.x;
    const int tx = tid & 15, ty = tid >> 4;
    const int bcol = blockIdx.x * 128, brow = blockIdx.y * 128;
    const int klo = (bcol >= BW) ? (bcol - BW) : 0;
    const int khi = min(IN_F, bcol + 128 + BW);
    float acc[8][8];
    #pragma unroll
    for (int a = 0; a < 8; ++a)
        #pragma unroll
        for (int b = 0; b < 8; ++b) acc[a][b] = 0.f;
    const int xc4 = (tid & 7) * 4, xr0 = tid >> 3;
    const int wc = tid & 31, wr0 = tid >> 5;
    for (int k0 = klo; k0 < khi; k0 += 32) {
        #pragma unroll
        for (int p = 0; p < 4; ++p) {
            const int rr = xr0 + 32 * p;
            const float4 v = *reinterpret_cast<const float4*>(&x[(size_t)(brow + rr) * IN_F + (k0 + xc4)]);
            Xs[rr][xc4 + 0] = v.x; Xs[rr][xc4 + 1] = v.y; Xs[rr][xc4 + 2] = v.z; Xs[rr][xc4 + 3] = v.w;
        }
        const int i = k0 + wc;
        #pragma unroll
        for (int p = 0; p < 16; ++p) {
            const int rr = wr0 + 8 * p;
            const int o = bcol + rr;
            const int lo = (o >= BW) ? (o - BW) : 0;
            float v = 0.f;
            if (i >= o - BW && i <= o + BW) v = wv[band_start(o) + (i - lo)];
            Ws[wc][rr] = v;
        }
        __syncthreads();
        #pragma unroll
        for (int k = 0; k < 32; ++k) {
            float amv[8];
            #pragma unroll
            for (int a = 0; a < 8; ++a) amv[a] = Xs[ty * 8 + a][k];
            float bo[8];
            #pragma unroll
            for (int b = 0; b < 4; ++b) { bo[b] = Ws[k][tx * 4 + b]; bo[4 + b] = Ws[k][tx * 4 + 64 + b]; }
            #pragma unroll
            for (int a = 0; a < 8; ++a)
                #pragma unroll
                for (int b = 0; b < 8; ++b) acc[a][b] = fmaf(amv[a], bo[b], acc[a][b]);
        }
        __syncthreads();
    }
    #pragma unroll
    for (int a = 0; a < 8; ++a) {
        const size_t row = (size_t)(brow + ty * 8 + a);
        #pragma unroll
        for (int b = 0; b < 4; ++b) {
            out[row * OUT_F + bcol + tx * 4 + b]      = acc[a][b]     + bias[bcol + tx * 4 + b];
            out[row * OUT_F + bcol + tx * 4 + 64 + b] = acc[a][4 + b] + bias[bcol + tx * 4 + 64 + b];
        }
    }
}

extern "C" void kernel_launch(void* const* d_in, const int* in_sizes, int n_in,
                              void* d_out, int out_size, void* d_ws, size_t ws_size,
                              hipStream_t stream) {
    const float* x    = (const float*)d_in[0];
    const float* wv   = (const float*)d_in[1];
    const float* bias = (const float*)d_in[2];
    float* out        = (float*)d_out;

    const int M = in_sizes[0] / IN_F;                         // 8192
    const size_t xb_bytes = (size_t)M * IN_F * 2;             // 64 MB
    const size_t wd_bytes = (size_t)OUT_F * WB2 * 2;          // 10.5 MB

    if (ws_size >= xb_bytes + wd_bytes && M == 8192) {
        uint16_t* xb  = (uint16_t*)d_ws;
        uint16_t* wdp = (uint16_t*)((uint8_t*)d_ws + xb_bytes);
        cvt_xw<<<2128, 256, 0, stream>>>(x, wv, xb, wdp, M * IN_F / 4);
        band_gemm_v10<<<256, 512, 0, stream>>>(xb, wdp, bias, out);
    } else {
        dim3 grid(OUT_F / 128, M / 128);
        band_gemm_f32<<<grid, 256, 0, stream>>>(x, wv, bias, out, M);
    }
}

// Round 14
// 136.076 us; speedup vs baseline: 1.9166x; 1.9166x over previous
//
#include <hip/hip_runtime.h>
#include <stdint.h>

#define IN_F  4096
#define OUT_F 4096
#define BW    512
#define WB2   1280   // padded k-window per 256-col tile: [bcol-512, bcol+768)
#define BM    256
#define BN    256

typedef __bf16 bf16x8 __attribute__((ext_vector_type(8)));
typedef float  f32x4  __attribute__((ext_vector_type(4)));

__device__ __forceinline__ int band_start(int o) {
    if (o <= 512)  return o * 513 + ((o * (o - 1)) >> 1);
    if (o <= 3584) return 393472 + (o - 512) * 1025;
    const int d = o - 3584;
    return 3542272 + (((1024 + 4609 - o) * d) >> 1);
}

__device__ __forceinline__ uint16_t f32_to_bf16(float f) {
    uint32_t u = __builtin_bit_cast(uint32_t, f);
    u += 0x7FFFu + ((u >> 16) & 1u);   // RNE
    return (uint16_t)(u >> 16);
}

// ---- pass 1 (single dispatch, BALANCED): every block grid-strides BOTH phases.
// Phase x: 8.4M float4 -> bf16x4 (16 iters/thread). Phase w: 1.31M ushort4 groups
// (~3 iters/thread, 8B coalesced stores).
__global__ __launch_bounds__(256) void cvt_xw(const float* __restrict__ x,
                                              const float* __restrict__ wv,
                                              uint16_t* __restrict__ xb,
                                              uint16_t* __restrict__ wd, int n4) {
    const int t = blockIdx.x * 256 + threadIdx.x;
    const int stride = 2048 * 256;

    for (int i = t; i < n4; i += stride) {
        const float4 v = reinterpret_cast<const float4*>(x)[i];
        const uint32_t lo = (uint32_t)f32_to_bf16(v.x) | ((uint32_t)f32_to_bf16(v.y) << 16);
        const uint32_t hi = (uint32_t)f32_to_bf16(v.z) | ((uint32_t)f32_to_bf16(v.w) << 16);
        reinterpret_cast<uint2*>(xb)[i] = make_uint2(lo, hi);
    }

    const int ng = OUT_F * (WB2 / 4);            // 1,310,720 ushort4 groups
    for (int g = t; g < ng; g += stride) {
        const int o  = g / (WB2 / 4);            // const-div -> magic mul
        const int j  = (g - o * (WB2 / 4)) * 4;
        const int i0 = (o & ~(BM - 1)) - BW + j;
        const int lo = (o > BW) ? (o - BW) : 0;
        const int hi = (o + BW < IN_F - 1) ? (o + BW) : (IN_F - 1);
        const int base = band_start(o) - lo;     // value index = i
        ushort4 vv;
        uint16_t* pv = (uint16_t*)&vv;
        #pragma unroll
        for (int e = 0; e < 4; ++e) {
            const int i = i0 + e;
            pv[e] = (i >= lo && i <= hi) ? f32_to_bf16(wv[base + i]) : (uint16_t)0;
        }
        *reinterpret_cast<ushort4*>(wd + (size_t)o * WB2 + j) = vv;
    }
}

// ---- pass 2: R10 GEMM verbatim (best measured: 95.6 us, MfmaUtil 33%, conflicts 0)
// ring-9 half-tile units (144 KB), counted vmcnt(2), ONE barrier per K64 tile,
// no setprio, persistent 2 row-jobs (1 block/CU), bx-grouped XCD mapping.
__global__ __launch_bounds__(512, 1) void band_gemm_v10(
    const uint16_t* __restrict__ xb,
    const uint16_t* __restrict__ wd,
    const float* __restrict__ bias,
    float* __restrict__ out)
{
    __shared__ __align__(128) uint8_t lds[9 * 16384];   // 144 KB, 9 unit slots

    const int id  = blockIdx.x;
    const int bx  = 2 * (id & 7) + ((id >> 3) & 1);
    const int byg = id >> 4;                 // rows byg and byg+16
    const int bcol = bx * BN;
    const int brow0 = byg * BM;

    const int wlo    = bcol - BW;
    const int kstart = wlo > 0 ? wlo : 0;
    const int kend   = (bcol + BN + BW) < IN_F ? (bcol + BN + BW) : IN_F;
    const int nt     = (kend - kstart) >> 6;      // 12/16/20 K64 tiles
    const int j0     = kstart - wlo;

    const int tid  = threadIdx.x;
    const int w    = tid >> 6;
    const int lane = tid & 63;
    const int ln   = lane & 15;
    const int kc   = lane >> 4;
    const int wm   = w >> 2;            // 0..1  (M half, 128 rows)
    const int wn   = w & 3;             // 0..3  (N quarter, 64 cols)

    const int srow = tid >> 3;          // 0..63
    const int csrc = (tid & 7) ^ (srow & 7);
    const uint16_t* aSrc0 = xb + (size_t)(brow0 + srow) * IN_F + kstart + csrc * 8;
    const uint16_t* aSrc1 = aSrc0 + (size_t)16 * BM * IN_F;      // rows +4096
    const uint16_t* bSrc  = wd + (size_t)(bcol + srow) * WB2 + j0 + csrc * 8;

#define GLOAD(srcp, dst_off)                                                             \
    __builtin_amdgcn_global_load_lds(                                                    \
        (const __attribute__((address_space(1))) uint32_t*)(srcp),                       \
        (__attribute__((address_space(3))) uint32_t*)(lds + (dst_off) + (w << 10)),      \
        16, 0, 0)

#define STG_UNIT(AS, w_, j_, slot_) {                                                    \
        if (((j_) & 1) == 0) {                                                           \
            const uint16_t* p_ = (AS) + (size_t)(((j_) >> 1) * 128) * IN_F + (w_) * 64;  \
            GLOAD(p_, (slot_) << 14);                                                    \
            GLOAD(p_ + (size_t)64 * IN_F, ((slot_) << 14) + 8192);                       \
        } else {                                                                         \
            const uint16_t* p_ = bSrc + (size_t)(((j_) >> 1) * 128) * WB2 + (w_) * 64;   \
            GLOAD(p_, (slot_) << 14);                                                    \
            GLOAD(p_ + (size_t)64 * WB2, ((slot_) << 14) + 8192);                        \
        } }

    const int cswz = (kc ^ (ln & 7)) << 4;

#define LD_A(BASE, MQ) {                                                                 \
    _Pragma("unroll")                                                                    \
    for (int s_ = 0; s_ < 4; ++s_) {                                                     \
        const int off_ = (BASE) + (((MQ) * 64 + s_ * 16 + ln) << 7) + cswz;              \
        am[s_][0] = *(const bf16x8*)(lds + off_);                                        \
        am[s_][1] = *(const bf16x8*)(lds + (off_ ^ 64));                                 \
    } }
#define LD_B(DST, BASE, NQ) {                                                            \
    _Pragma("unroll")                                                                    \
    for (int s_ = 0; s_ < 2; ++s_) {                                                     \
        const int off_ = (BASE) + (((wn & 1) * 64 + (NQ) * 32 + s_ * 16 + ln) << 7) + cswz; \
        DST[s_][0] = *(const bf16x8*)(lds + off_);                                       \
        DST[s_][1] = *(const bf16x8*)(lds + (off_ ^ 64));                                \
    } }
#define MFMAPH(MROW, NCOL, BB) {                                                         \
    _Pragma("unroll")                                                                    \
    for (int a_ = 0; a_ < 4; ++a_) {                                                     \
        _Pragma("unroll")                                                                \
        for (int n_ = 0; n_ < 2; ++n_) {                                                 \
            acc[(MROW) + a_][(NCOL) + n_] = __builtin_amdgcn_mfma_f32_16x16x32_bf16(     \
                am[a_][0], BB[n_][0], acc[(MROW) + a_][(NCOL) + n_], 0, 0, 0);           \
            acc[(MROW) + a_][(NCOL) + n_] = __builtin_amdgcn_mfma_f32_16x16x32_bf16(     \
                am[a_][1], BB[n_][1], acc[(MROW) + a_][(NCOL) + n_], 0, 0, 0);           \
        } } }

#define PRO(AS) {                                                                        \
    STG_UNIT(AS, 0, 0, 0); STG_UNIT(AS, 0, 1, 1); STG_UNIT(AS, 0, 2, 2);                 \
    STG_UNIT(AS, 0, 3, 3); STG_UNIT(AS, 1, 0, 4); }

#define KLOOP(AS) {                                                                      \
    int s4v = 0;                                                                         \
    for (int v = 0; v < nt; ++v) {                                                       \
        int sA = s4v + (wm << 1);            if (sA >= 9) sA -= 9;                       \
        int sB = s4v + 1 + ((wn >> 1) << 1); if (sB >= 9) sB -= 9;                       \
        const int aBase = sA << 14, bBase = sB << 14;                                    \
        int st0 = s4v + 5; if (st0 >= 9) st0 -= 9;                                       \
        int st1 = st0 + 1; if (st1 >= 9) st1 -= 9;                                       \
        int st2 = st1 + 1; if (st2 >= 9) st2 -= 9;                                       \
        int st3 = st2 + 1; if (st3 >= 9) st3 -= 9;                                       \
        const bool stg_q012 = (v + 1 < nt);                                              \
        const bool stg_q3   = (v + 2 < nt);                                              \
        LD_A(aBase, 0);                                                                  \
        LD_B(bn0, bBase, 0);                                                             \
        if (stg_q012) STG_UNIT(AS, v + 1, 1, st0);                                       \
        MFMAPH(0, 0, bn0);                                                               \
        LD_B(bn1, bBase, 1);                                                             \
        if (stg_q012) STG_UNIT(AS, v + 1, 2, st1);                                       \
        MFMAPH(0, 2, bn1);                                                               \
        LD_A(aBase, 1);                                                                  \
        if (stg_q012) STG_UNIT(AS, v + 1, 3, st2);                                       \
        MFMAPH(4, 2, bn1);                                                               \
        if (stg_q3) STG_UNIT(AS, v + 2, 0, st3);                                         \
        MFMAPH(4, 0, bn0);                                                               \
        if (v + 1 < nt) {                                                                \
            if (v + 2 < nt) { asm volatile("s_waitcnt vmcnt(2)" ::: "memory"); }         \
            else            { asm volatile("s_waitcnt vmcnt(0)" ::: "memory"); }         \
            __builtin_amdgcn_s_barrier();                                                \
        }                                                                                \
        s4v += 4; if (s4v >= 9) s4v -= 9;                                                \
    } }

#define EPI(BROWX) {                                                                     \
    _Pragma("unroll")                                                                    \
    for (int a_ = 0; a_ < 8; ++a_) {                                                     \
        _Pragma("unroll")                                                                \
        for (int q_ = 0; q_ < 4; ++q_) {                                                 \
            const int row_ = (BROWX) + wm * 128 + a_ * 16 + (kc << 2) + q_;              \
            float* po_ = out + (size_t)row_ * OUT_F + ocol;                              \
            _Pragma("unroll")                                                            \
            for (int n_ = 0; n_ < 4; ++n_)                                               \
                po_[n_ * 16] = acc[a_][n_][q_] + bsv[n_];                                 \
        } } }

    const int ocol = bcol + wn * 64 + ln;
    float bsv[4];
    #pragma unroll
    for (int n = 0; n < 4; ++n) bsv[n] = bias[ocol + n * 16];

    f32x4 acc[8][4] = {};
    bf16x8 am[4][2], bn0[2][2], bn1[2][2];

    // ---- row-tile g=0
    PRO(aSrc0);
    asm volatile("s_waitcnt vmcnt(2)" ::: "memory");
    __builtin_amdgcn_s_barrier();
    KLOOP(aSrc0);
    __builtin_amdgcn_s_barrier();            // slot safety: all g0 reads complete

    // ---- g=1 prologue; epilogue-0 stores drain under g1 compute
    PRO(aSrc1);
    asm volatile("s_waitcnt vmcnt(2)" ::: "memory");
    __builtin_amdgcn_s_barrier();
    EPI(brow0);
    #pragma unroll
    for (int a = 0; a < 8; ++a)
        #pragma unroll
        for (int n = 0; n < 4; ++n) acc[a][n] = (f32x4){0.f, 0.f, 0.f, 0.f};
    KLOOP(aSrc1);
    EPI(brow0 + 16 * BM);

#undef STG_UNIT
#undef GLOAD
#undef PRO
#undef KLOOP
#undef EPI
}

// ---- fallback (ws too small / odd M): fp32 tiled kernel, known correct
__global__ __launch_bounds__(256) void band_gemm_f32(
    const float* __restrict__ x, const float* __restrict__ wv,
    const float* __restrict__ bias, float* __restrict__ out, int M)
{
    __shared__ float Xs[128][33];
    __shared__ float Ws[32][130];
    const int tid = threadIdx.x;
    const int tx = tid & 15, ty = tid >> 4;
    const int bcol = blockIdx.x * 128, brow = blockIdx.y * 128;
    const int klo = (bcol >= BW) ? (bcol - BW) : 0;
    const int khi = min(IN_F, bcol + 128 + BW);
    float acc[8][8];
    #pragma unroll
    for (int a = 0; a < 8; ++a)
        #pragma unroll
        for (int b = 0; b < 8; ++b) acc[a][b] = 0.f;
    const int xc4 = (tid & 7) * 4, xr0 = tid >> 3;
    const int wc = tid & 31, wr0 = tid >> 5;
    for (int k0 = klo; k0 < khi; k0 += 32) {
        #pragma unroll
        for (int p = 0; p < 4; ++p) {
            const int rr = xr0 + 32 * p;
            const float4 v = *reinterpret_cast<const float4*>(&x[(size_t)(brow + rr) * IN_F + (k0 + xc4)]);
            Xs[rr][xc4 + 0] = v.x; Xs[rr][xc4 + 1] = v.y; Xs[rr][xc4 + 2] = v.z; Xs[rr][xc4 + 3] = v.w;
        }
        const int i = k0 + wc;
        #pragma unroll
        for (int p = 0; p < 16; ++p) {
            const int rr = wr0 + 8 * p;
            const int o = bcol + rr;
            const int lo = (o >= BW) ? (o - BW) : 0;
            float v = 0.f;
            if (i >= o - BW && i <= o + BW) v = wv[band_start(o) + (i - lo)];
            Ws[wc][rr] = v;
        }
        __syncthreads();
        #pragma unroll
        for (int k = 0; k < 32; ++k) {
            float amv[8];
            #pragma unroll
            for (int a = 0; a < 8; ++a) amv[a] = Xs[ty * 8 + a][k];
            float bo[8];
            #pragma unroll
            for (int b = 0; b < 4; ++b) { bo[b] = Ws[k][tx * 4 + b]; bo[4 + b] = Ws[k][tx * 4 + 64 + b]; }
            #pragma unroll
            for (int a = 0; a < 8; ++a)
                #pragma unroll
                for (int b = 0; b < 8; ++b) acc[a][b] = fmaf(amv[a], bo[b], acc[a][b]);
        }
        __syncthreads();
    }
    #pragma unroll
    for (int a = 0; a < 8; ++a) {
        const size_t row = (size_t)(brow + ty * 8 + a);
        #pragma unroll
        for (int b = 0; b < 4; ++b) {
            out[row * OUT_F + bcol + tx * 4 + b]      = acc[a][b]     + bias[bcol + tx * 4 + b];
            out[row * OUT_F + bcol + tx * 4 + 64 + b] = acc[a][4 + b] + bias[bcol + tx * 4 + 64 + b];
        }
    }
}

extern "C" void kernel_launch(void* const* d_in, const int* in_sizes, int n_in,
                              void* d_out, int out_size, void* d_ws, size_t ws_size,
                              hipStream_t stream) {
    const float* x    = (const float*)d_in[0];
    const float* wv   = (const float*)d_in[1];
    const float* bias = (const float*)d_in[2];
    float* out        = (float*)d_out;

    const int M = in_sizes[0] / IN_F;                         // 8192
    const size_t xb_bytes = (size_t)M * IN_F * 2;             // 64 MB
    const size_t wd_bytes = (size_t)OUT_F * WB2 * 2;          // 10.5 MB

    if (ws_size >= xb_bytes + wd_bytes && M == 8192) {
        uint16_t* xb  = (uint16_t*)d_ws;
        uint16_t* wdp = (uint16_t*)((uint8_t*)d_ws + xb_bytes);
        cvt_xw<<<2048, 256, 0, stream>>>(x, wv, xb, wdp, M * IN_F / 4);
        band_gemm_v10<<<256, 512, 0, stream>>>(xb, wdp, bias, out);
    } else {
        dim3 grid(OUT_F / 128, M / 128);
        band_gemm_f32<<<grid, 256, 0, stream>>>(x, wv, bias, out, M);
    }
}